// Round 16
// baseline (402.977 us; speedup 1.0000x reference)
//
#include <hip/hip_runtime.h>
#include <stdint.h>

#define NB 8
#define F_IN 6300
#define NT 500
#define HID 32
#define NOUT 20
#define NW 99   // u64 mask words per (b,t) row: ceil(6300/64)

// float32 constants, rounded exactly as np.float32 would round the doubles
#define D_SR   0.7788007830714049f     // exp(-1/4)
#define S_SR   0.6795704571147613f     // e/4
#define D_REF  0.36787944117144233f    // exp(-1)
#define C_REF  -5.43656365691809f      // -2*e

// ---------------- K0: transpose w1 [32][6300] -> w1t [6300][32] (f32) ----------------
__global__ __launch_bounds__(256) void k0_transpose(const float* __restrict__ w1,
                                                    float* __restrict__ w1t) {
  __shared__ float tl[64][33];
  const int f0 = blockIdx.x * 64;
  const int tid = threadIdx.x;
  const int r = tid & 63, g = tid >> 6;
#pragma unroll
  for (int oo = 0; oo < 32; oo += 4) {
    int o = oo + g;
    int f = f0 + r;
    tl[r][o] = (f < F_IN) ? w1[o * F_IN + f] : 0.f;
  }
  __syncthreads();
#pragma unroll
  for (int k = 0; k < 8; k++) {
    int idx = k * 256 + tid;
    int rr = idx >> 5, cc = idx & 31;
    int f = f0 + rr;
    if (f < F_IN) w1t[(size_t)f * 32 + cc] = tl[rr][cc];
  }
}

// ---------------- K1: layer 1 (psp -> spike), exact-order f32, 2 chains/wave ----------------
// One wave handles TWO 64-channel words: two independent recurrence chains per lane,
// interleaved so one chain's dependency-latency bubbles are filled by the other's
// issue (single wave/SIMD has no TLP; ILP is the only filler). Bit-exact per channel.
#define CH_T 100

__global__ __launch_bounds__(64, 1) void k1_layer1(const float* __restrict__ x,
                                                   uint64_t* __restrict__ masks) {
  __shared__ __align__(16) float tile[128 * 100];   // 51.2 KB
  const int wg = blockIdx.x;          // word pair: words 2wg, 2wg+1
  const int b  = blockIdx.y;
  const int lane = threadIdx.x;
  const float* xblk = x + (size_t)b * F_IN * NT;

  const int word0 = 2 * wg, word1 = 2 * wg + 1;
  const uint64_t vm0 = __ballot(word0 * 64 + lane < F_IN);
  const uint64_t vm1 = __ballot(word1 * 64 + lane < F_IN);

  int offA[25], offB[25], dA[25];
#pragma unroll
  for (int k = 0; k < 25; k++) {
    int idx = k * 64 + lane;
    int fid = idx / 25;            // 0..63
    int j25 = idx - fid * 25;
    int chA = wg * 128 + fid;       if (chA >= F_IN) chA = F_IN - 1;  // clamp (vm masks)
    int chB = wg * 128 + 64 + fid;  if (chB >= F_IN) chB = F_IN - 1;
    offA[k] = chA * NT + 4 * j25;
    offB[k] = chB * NT + 4 * j25;
    dA[k]   = fid * 100 + 4 * j25;  // bank quad = idx mod 32 -> uniform
  }

  float z1a = 0.f, y1a = 0.f, zra = 0.f, yra = 0.f;
  float z1b = 0.f, y1b = 0.f, zrb = 0.f, yrb = 0.f;

#pragma unroll 1
  for (int c = 0; c < 5; c++) {
    const float* gb = xblk + c * CH_T;
#pragma unroll
    for (int k = 0; k < 25; k++) {
      float4 v = *(const float4*)(gb + offA[k]);
      *(float4*)(&tile[dA[k]]) = v;
    }
#pragma unroll
    for (int k = 0; k < 25; k++) {
      float4 v = *(const float4*)(gb + offB[k]);
      *(float4*)(&tile[6400 + dA[k]]) = v;
    }
    const float4* lrow0 = (const float4*)&tile[lane * 100];         // quad 25*lane+g: uniform
    const float4* lrow1 = (const float4*)&tile[(64 + lane) * 100];
    float4 rb0[4], rb1[4];
#pragma unroll
    for (int i = 0; i < 4; i++) { rb0[i] = lrow0[i]; rb1[i] = lrow1[i]; }
    uint64_t k00 = 0, k01 = 0, k10 = 0, k11 = 0;   // keep[chain][t-half]
#pragma unroll
    for (int g = 0; g < 25; g++) {
      float4 xq0 = rb0[g & 3], xq1 = rb1[g & 3];
      if (g + 4 < 25) { rb0[g & 3] = lrow0[g + 4]; rb1[g & 3] = lrow1[g + 4]; }
      float xs0[4] = {xq0.x, xq0.y, xq0.z, xq0.w};
      float xs1[4] = {xq1.x, xq1.y, xq1.z, xq1.w};
#pragma unroll
      for (int e = 0; e < 4; e++) {
        const int tc = g * 4 + e;      // compile-time 0..99
        // chain 0 (word0) -- exact reference order
        y1a = __fmul_rn(D_SR, __fadd_rn(y1a, z1a));
        z1a = __fadd_rn(__fmul_rn(D_SR, z1a), xs0[e]);
        float pa = __fmul_rn(S_SR, y1a);
        yra = __fmul_rn(D_REF, __fadd_rn(yra, zra));
        float ua = __fadd_rn(pa, __fmul_rn(C_REF, yra));
        bool sa = (ua >= 1.0f);
        zra = __fadd_rn(__fmul_rn(D_REF, zra), sa ? 1.0f : 0.0f);
        // chain 1 (word1) -- independent, fills chain 0's latency bubbles
        y1b = __fmul_rn(D_SR, __fadd_rn(y1b, z1b));
        z1b = __fadd_rn(__fmul_rn(D_SR, z1b), xs1[e]);
        float pb = __fmul_rn(S_SR, y1b);
        yrb = __fmul_rn(D_REF, __fadd_rn(yrb, zrb));
        float ub = __fadd_rn(pb, __fmul_rn(C_REF, yrb));
        bool sb = (ub >= 1.0f);
        zrb = __fadd_rn(__fmul_rn(D_REF, zrb), sb ? 1.0f : 0.0f);
        uint64_t m0 = __ballot(sa);
        uint64_t m1 = __ballot(sb);
        if (tc < 64) { if (lane == tc)      { k00 = m0; k10 = m1; } }
        else         { if (lane == tc - 64) { k01 = m0; k11 = m1; } }
      }
    }
    // coalesced mask writeback (invalid-channel bits cleared once here)
    uint64_t* mp0 = masks + ((size_t)b * NW + word0) * NT + c * CH_T;
    mp0[lane] = k00 & vm0;
    if (lane < CH_T - 64) mp0[64 + lane] = k01 & vm0;
    if (word1 < NW) {
      uint64_t* mp1 = masks + ((size_t)b * NW + word1) * NT + c * CH_T;
      mp1[lane] = k10 & vm1;
      if (lane < CH_T - 64) mp1[64 + lane] = k11 & vm1;
    }
  }
}

// ---------------- K2: sparse fc1: R[b,o,t] = sum_{f active} w1t[f][o] (f64) ----------------
// 1024-thread blocks: 16 waves = 4 t x 4 f-segments; halves take even/odd u64 words.
__global__ __launch_bounds__(1024) void k2_fc1(const float* __restrict__ w1t,
                                               const uint64_t* __restrict__ masks,
                                               double* __restrict__ R) {
  __shared__ double part[16][32];
  const int tid = threadIdx.x;
  const int wv = tid >> 6;            // 0..15
  const int lane = tid & 63;
  const int half = lane >> 5;
  const int o = lane & 31;
  const int b = blockIdx.x;
  const int t = blockIdx.y * 4 + (wv & 3);
  const int seg = wv >> 2;            // 0..3: words [25s, min(25s+25,99))
  const int wbeg = seg * 25;
  const int wend = (seg == 3) ? NW : (wbeg + 25);
  const uint64_t* mbase = masks + (size_t)b * NW * NT + t;
  const char* wrow = (const char*)w1t + o * 4;
  double acc0 = 0.0, acc1 = 0.0, acc2 = 0.0, acc3 = 0.0;

  int wi = wbeg + half;
  uint64_t mcur = (wi < wend) ? mbase[(size_t)wi * NT] : 0;
  for (; wi < wend; wi += 2) {
    uint64_t mnext = (wi + 2 < wend) ? mbase[(size_t)(wi + 2) * NT] : 0;
    const uint32_t base0 = ((uint32_t)wi << 13);
    uint32_t w = (uint32_t)mcur;
    uint32_t boff = base0;
#pragma unroll
    for (int sub = 0; sub < 2; sub++) {
      while (w) {
        uint32_t i0 = __builtin_ctz(w);                 uint32_t w1_ = w & (w - 1);
        uint32_t i1 = w1_ ? __builtin_ctz(w1_) : 0u;    uint32_t w2_ = w1_ ? (w1_ & (w1_ - 1)) : 0u;
        uint32_t i2 = w2_ ? __builtin_ctz(w2_) : 0u;    uint32_t w3_ = w2_ ? (w2_ & (w2_ - 1)) : 0u;
        uint32_t i3 = w3_ ? __builtin_ctz(w3_) : 0u;    w = w3_ ? (w3_ & (w3_ - 1)) : 0u;
        float a0 = *(const float*)(wrow + boff + (i0 << 7));
        float a1 = *(const float*)(wrow + boff + (i1 << 7));
        float a2 = *(const float*)(wrow + boff + (i2 << 7));
        float a3 = *(const float*)(wrow + boff + (i3 << 7));
        a1 = w1_ ? a1 : 0.0f;
        a2 = w2_ ? a2 : 0.0f;
        a3 = w3_ ? a3 : 0.0f;
        acc0 += (double)a0;     // 4 independent chains
        acc1 += (double)a1;
        acc2 += (double)a2;
        acc3 += (double)a3;
      }
      w = (uint32_t)(mcur >> 32);
      boff = base0 + (32u << 7);
    }
    mcur = mnext;
  }
  double acc = (acc0 + acc1) + (acc2 + acc3);
  int hi2 = __shfl_xor(__double2hiint(acc), 32);
  int lo2 = __shfl_xor(__double2loint(acc), 32);
  acc += __hiloint2double(hi2, lo2);
  if (half == 0) part[wv][o] = acc;
  __syncthreads();
  if (wv < 4 && half == 0) {
    // ascending-f segment order
    double tot = ((part[wv][o] + part[wv + 4][o]) + part[wv + 8][o]) + part[wv + 12][o];
    R[((size_t)b * HID + o) * NT + (blockIdx.y * 4 + wv)] = tot;
  }
}

// ---------------- fast f64 psp+spike step: speculative-select short chain ----------------
#define SNN_FAST_STEP(rin, EMIT)                                                \
  {                                                                             \
    y2 = __builtin_fma(dsr, y2, w);          /* y2_t */                         \
    z2 = __builtin_fma(dsr, z2, (rin));      /* z2_t */                         \
    w  = dsr * z2;                                                              \
    double p  = ssr * y2;                                                       \
    double u0 = __builtin_fma(cr, q, p);                                        \
    double u1 = u0 + K;                                                         \
    double u  = sp ? u1 : u0;                                                   \
    bool s = (u >= 1.0);                                                        \
    double yr = q + (sp ? dre : 0.0);        /* yr_t */                         \
    double zr = zrd + (sp ? 1.0 : 0.0);      /* zr_{t-1} */                     \
    zrd = dre * zr;                                                             \
    q = __builtin_fma(dre, yr, dre * zrd);   /* q_t */                          \
    sp = s;                                                                     \
    EMIT                                                                        \
  }

// ---------------- K3: layer-2 psp+spike -> s2m[b][t] uint32 bitmask ----------------
__global__ __launch_bounds__(64) void k3_spike2(const double* __restrict__ R,
                                                uint32_t* __restrict__ s2m) {
  const int blk = blockIdx.x;
  const int lane = threadIdx.x;
  const int half = lane >> 5;
  const int b = blk * 2 + half;
  const int h = lane & 31;
  const double2* r2 = (const double2*)(R + ((size_t)b * HID + h) * NT);
  uint32_t* m0 = s2m + (size_t)(blk * 2) * NT;
  uint32_t* m1 = s2m + (size_t)(blk * 2 + 1) * NT;

  const double dsr = (double)D_SR, ssr = (double)S_SR;
  const double dre = (double)D_REF, cr = (double)C_REF;
  const double K = cr * dre;
  double y2 = 0, z2 = 0, w = 0, q = 0, zrd = 0;
  bool sp = false;

  double2 bufa[8], bufb[8];
#pragma unroll
  for (int i = 0; i < 8; i++) { bufa[i] = r2[i * 2]; bufb[i] = r2[i * 2 + 1]; }

  for (int g8 = 0; g8 < 16; g8++) {
#pragma unroll
    for (int j = 0; j < 8; j++) {
      const int g = g8 * 8 + j;
      if (g >= 125) break;
      const int t = g * 4;
      double2 va = bufa[j], vb = bufb[j];
      SNN_FAST_STEP(va.x, { uint64_t m = __ballot(s);
        if (lane == 0) { m0[t] = (uint32_t)m; m1[t] = (uint32_t)(m >> 32); } })
      SNN_FAST_STEP(va.y, { uint64_t m = __ballot(s);
        if (lane == 0) { m0[t + 1] = (uint32_t)m; m1[t + 1] = (uint32_t)(m >> 32); } })
      SNN_FAST_STEP(vb.x, { uint64_t m = __ballot(s);
        if (lane == 0) { m0[t + 2] = (uint32_t)m; m1[t + 2] = (uint32_t)(m >> 32); } })
      SNN_FAST_STEP(vb.y, { uint64_t m = __ballot(s);
        if (lane == 0) { m0[t + 3] = (uint32_t)m; m1[t + 3] = (uint32_t)(m >> 32); } })
      if (g + 8 < 125) { bufa[j] = r2[(g + 8) * 2]; bufb[j] = r2[(g + 8) * 2 + 1]; }
    }
  }
}

// ---------------- K4: R3[b,o,t] = sum_h w2[o,h]*s2[t,h] via mask (f64, asc h) ----------------
__global__ __launch_bounds__(256) void k4_fc2(const float* __restrict__ w2,
                                              const uint32_t* __restrict__ s2m,
                                              double* __restrict__ R3) {
  __shared__ float w2l[NOUT * HID];
  const int tid = threadIdx.x;
  for (int i = tid; i < NOUT * HID; i += 256) w2l[i] = w2[i];
  __syncthreads();
  int id = blockIdx.x * 256 + tid;
  if (id >= NB * NOUT * NT) return;
  int t = id % NT;
  int bo = id / NT;
  int o = bo % NOUT;
  int b = bo / NOUT;
  uint32_t m = s2m[(size_t)b * NT + t];
  const float* wr = w2l + o * HID;
  double acc = 0.0;
  while (m) {
    uint32_t i0 = __builtin_ctz(m);                 uint32_t m1_ = m & (m - 1);
    uint32_t i1 = m1_ ? __builtin_ctz(m1_) : 0u;    uint32_t m2_ = m1_ ? (m1_ & (m1_ - 1)) : 0u;
    uint32_t i2 = m2_ ? __builtin_ctz(m2_) : 0u;    uint32_t m3_ = m2_ ? (m2_ & (m2_ - 1)) : 0u;
    uint32_t i3 = m3_ ? __builtin_ctz(m3_) : 0u;    m = m3_ ? (m3_ & (m3_ - 1)) : 0u;
    float a0 = wr[i0];
    float a1 = m1_ ? wr[i1] : 0.0f;
    float a2 = m2_ ? wr[i2] : 0.0f;
    float a3 = m3_ ? wr[i3] : 0.0f;
    acc += (double)a0;
    acc += (double)a1;
    acc += (double)a2;
    acc += (double)a3;
  }
  R3[id] = acc;   // [b][o][t] coalesced
}

// ---------------- K5: layer-3 psp+spike -> output f32 [b,o,t] ----------------
__global__ __launch_bounds__(64) void k5_out(const double* __restrict__ R3,
                                             float* __restrict__ out) {
  int id = blockIdx.x * 64 + threadIdx.x;
  if (id >= NB * NOUT) return;
  const double2* r2 = (const double2*)(R3 + (size_t)id * NT);
  float* orow = out + (size_t)id * NT;

  const double dsr = (double)D_SR, ssr = (double)S_SR;
  const double dre = (double)D_REF, cr = (double)C_REF;
  const double K = cr * dre;
  double y2 = 0, z2 = 0, w = 0, q = 0, zrd = 0;
  bool sp = false;

  double2 bufa[8], bufb[8];
#pragma unroll
  for (int i = 0; i < 8; i++) { bufa[i] = r2[i * 2]; bufb[i] = r2[i * 2 + 1]; }

  for (int g8 = 0; g8 < 16; g8++) {
#pragma unroll
    for (int j = 0; j < 8; j++) {
      const int g = g8 * 8 + j;
      if (g >= 125) break;
      double2 va = bufa[j], vb = bufb[j];
      float4 ov;
      SNN_FAST_STEP(va.x, { ov.x = s ? 1.0f : 0.0f; })
      SNN_FAST_STEP(va.y, { ov.y = s ? 1.0f : 0.0f; })
      SNN_FAST_STEP(vb.x, { ov.z = s ? 1.0f : 0.0f; })
      SNN_FAST_STEP(vb.y, { ov.w = s ? 1.0f : 0.0f; })
      *(float4*)(orow + g * 4) = ov;
      if (g + 8 < 125) { bufa[j] = r2[(g + 8) * 2]; bufb[j] = r2[(g + 8) * 2 + 1]; }
    }
  }
}

extern "C" void kernel_launch(void* const* d_in, const int* in_sizes, int n_in,
                              void* d_out, int out_size, void* d_ws, size_t ws_size,
                              hipStream_t stream) {
  const float* x  = (const float*)d_in[0];   // [8,6300,500]
  const float* w1 = (const float*)d_in[1];   // [32,6300]
  const float* w2 = (const float*)d_in[2];   // [20,32]
  float* out = (float*)d_out;                // [8,20,500]

  uint8_t* ws = (uint8_t*)d_ws;
  const size_t W1T_BYTES  = (size_t)F_IN * HID * 4;        //   806,400
  const size_t MASK_BYTES = (size_t)NB * NW * NT * 8;      // 3,168,000
  const size_t R_BYTES    = (size_t)NB * HID * NT * 8;     // 1,024,000
  const size_t S2M_BYTES  = (size_t)NB * NT * 4;           //    16,000
  float*    w1t   = (float*)ws;
  uint64_t* masks = (uint64_t*)(ws + W1T_BYTES);
  double*   R     = (double*)(ws + W1T_BYTES + MASK_BYTES);
  uint32_t* s2m   = (uint32_t*)(ws + W1T_BYTES + MASK_BYTES + R_BYTES);
  double*   R3    = (double*)(ws + W1T_BYTES + MASK_BYTES + R_BYTES + S2M_BYTES);

  k0_transpose<<<99, 256, 0, stream>>>(w1, w1t);
  k1_layer1<<<dim3(50, NB), 64, 0, stream>>>(x, masks);
  k2_fc1<<<dim3(NB, NT / 4), 1024, 0, stream>>>(w1t, masks, R);
  k3_spike2<<<4, 64, 0, stream>>>(R, s2m);
  k4_fc2<<<(NB * NOUT * NT + 255) / 256, 256, 0, stream>>>(w2, s2m, R3);
  k5_out<<<3, 64, 0, stream>>>(R3, out);
}

// Round 17
// 280.621 us; speedup vs baseline: 1.4360x; 1.4360x over previous
//
#include <hip/hip_runtime.h>
#include <stdint.h>

#define NB 8
#define F_IN 6300
#define NT 500
#define HID 32
#define NOUT 20
#define NW 99   // u64 mask words per (b,t) row: ceil(6300/64)

// float32 constants, rounded exactly as np.float32 would round the doubles
#define D_SR   0.7788007830714049f     // exp(-1/4)
#define S_SR   0.6795704571147613f     // e/4
#define D_REF  0.36787944117144233f    // exp(-1)
#define C_REF  -5.43656365691809f      // -2*e

// ---------------- K0: transpose w1 [32][6300] -> w1t [6300][32] (f32) ----------------
__global__ __launch_bounds__(256) void k0_transpose(const float* __restrict__ w1,
                                                    float* __restrict__ w1t) {
  __shared__ float tl[64][33];
  const int f0 = blockIdx.x * 64;
  const int tid = threadIdx.x;
  const int r = tid & 63, g = tid >> 6;
#pragma unroll
  for (int oo = 0; oo < 32; oo += 4) {
    int o = oo + g;
    int f = f0 + r;
    tl[r][o] = (f < F_IN) ? w1[o * F_IN + f] : 0.f;
  }
  __syncthreads();
#pragma unroll
  for (int k = 0; k < 8; k++) {
    int idx = k * 256 + tid;
    int rr = idx >> 5, cc = idx & 31;
    int f = f0 + rr;
    if (f < F_IN) w1t[(size_t)f * 32 + cc] = tl[rr][cc];
  }
}

// ---------------- K1: layer 1 (psp -> spike), exact-order f32 ----------------
// One wave per (b, 64-f word); single serial chain per lane (measured floor:
// ~59 us — ILP interleave, prefetch rings, and layout changes all failed to beat it).
#define CH_T 100

__global__ __launch_bounds__(64, 1) void k1_layer1(const float* __restrict__ x,
                                                   uint64_t* __restrict__ masks) {
  __shared__ __align__(16) float tileT[64][104];   // 26.6 KB
  const int wi = blockIdx.x;
  const int b  = blockIdx.y;
  const int lane = threadIdx.x;
  const int f = wi * 64 + lane;
  const uint64_t vmask = __ballot(f < F_IN);   // wave-constant validity mask
  const float* xblk = x + (size_t)b * F_IN * NT;
  uint64_t* mrow = masks + ((size_t)b * NW + wi) * NT;

  int goff[25], doff[25];
#pragma unroll
  for (int k = 0; k < 25; k++) {
    int idx = k * 64 + lane;
    int fid = idx / 25;
    int j = idx - fid * 25;
    int rf = wi * 64 + fid;
    if (rf >= F_IN) rf = F_IN - 1;   // clamp: in-bounds reads; bits masked by vmask
    goff[k] = rf * NT + 4 * j;       // global float4 offset (dwords)
    doff[k] = fid * 104 + 4 * j;     // LDS deposit offset (dwords)
  }

  float z1 = 0.f, y1 = 0.f, zr = 0.f, yr = 0.f;
  float* tbase = &tileT[0][0];

#pragma unroll 1
  for (int c = 0; c < 5; c++) {
    // load chunk c (25 independent dwordx4, coalesced along t); 25 b128 LDS writes
    const float* gb = xblk + c * CH_T;
    float4 ld[25];
#pragma unroll
    for (int k = 0; k < 25; k++) ld[k] = *(const float4*)(gb + goff[k]);
#pragma unroll
    for (int k = 0; k < 25; k++) *(float4*)(tbase + doff[k]) = ld[k];

    // compute 100 t in 25 groups of 4; one b128 read per group, 4-slot static ring
    const float4* lrow = (const float4*)&tileT[lane][0];   // 26 aligned float4 slots
    float4 rbuf[4];
#pragma unroll
    for (int i = 0; i < 4; i++) rbuf[i] = lrow[i];
    uint64_t keep0 = 0, keep1 = 0;
#pragma unroll
    for (int g = 0; g < 25; g++) {
      float4 xq = rbuf[g & 3];
      if (g + 4 < 25) rbuf[g & 3] = lrow[g + 4];
      float xs[4] = {xq.x, xq.y, xq.z, xq.w};
#pragma unroll
      for (int e = 0; e < 4; e++) {
        const int tc = g * 4 + e;      // compile-time 0..99
        float xi = xs[e];
        y1 = __fmul_rn(D_SR, __fadd_rn(y1, z1));        // y = d*(y+z)
        z1 = __fadd_rn(__fmul_rn(D_SR, z1), xi);        // z = d*z + x
        float p = __fmul_rn(S_SR, y1);
        yr = __fmul_rn(D_REF, __fadd_rn(yr, zr));
        float u = __fadd_rn(p, __fmul_rn(C_REF, yr));
        bool s = (u >= 1.0f);
        zr = __fadd_rn(__fmul_rn(D_REF, zr), s ? 1.0f : 0.0f);
        uint64_t m = __ballot(s);
        if (tc < 64) { if (lane == tc)      keep0 = m; }
        else         { if (lane == tc - 64) keep1 = m; }
      }
    }
    // coalesced mask writeback (invalid-channel bits cleared once here)
    uint64_t* mp = mrow + c * CH_T;
    mp[lane] = keep0 & vmask;
    if (lane < CH_T - 64) mp[64 + lane] = keep1 & vmask;
  }
}

// ---------------- K2: sparse fc1: R[b,o,t] = sum_{f active} w1t[f][o] (f64) ----------------
// 512-thread blocks: 8 waves = 4 t x 2 f-segments; halves take even/odd u64 words.
// 4-way batched extraction with 4 independent f64 accumulators.
__global__ __launch_bounds__(512) void k2_fc1(const float* __restrict__ w1t,
                                              const uint64_t* __restrict__ masks,
                                              double* __restrict__ R) {
  __shared__ double part[8][32];
  const int tid = threadIdx.x;
  const int wv = tid >> 6;
  const int lane = tid & 63;
  const int half = lane >> 5;
  const int o = lane & 31;
  const int b = blockIdx.x;
  const int t = blockIdx.y * 4 + (wv & 3);
  const int seg = wv >> 2;
  const int wbeg = seg * 50, wend = seg ? NW : 50;
  const uint64_t* mbase = masks + (size_t)b * NW * NT + t;
  const char* wrow = (const char*)w1t + o * 4;
  double acc0 = 0.0, acc1 = 0.0, acc2 = 0.0, acc3 = 0.0;

  int wi = wbeg + half;
  uint64_t mcur = (wi < wend) ? mbase[(size_t)wi * NT] : 0;
  for (; wi < wend; wi += 2) {
    uint64_t mnext = (wi + 2 < wend) ? mbase[(size_t)(wi + 2) * NT] : 0;
    const uint32_t base0 = ((uint32_t)wi << 13);
    uint32_t w = (uint32_t)mcur;
    uint32_t boff = base0;
#pragma unroll
    for (int sub = 0; sub < 2; sub++) {
      while (w) {
        uint32_t i0 = __builtin_ctz(w);                 uint32_t w1_ = w & (w - 1);
        uint32_t i1 = w1_ ? __builtin_ctz(w1_) : 0u;    uint32_t w2_ = w1_ ? (w1_ & (w1_ - 1)) : 0u;
        uint32_t i2 = w2_ ? __builtin_ctz(w2_) : 0u;    uint32_t w3_ = w2_ ? (w2_ & (w2_ - 1)) : 0u;
        uint32_t i3 = w3_ ? __builtin_ctz(w3_) : 0u;    w = w3_ ? (w3_ & (w3_ - 1)) : 0u;
        float a0 = *(const float*)(wrow + boff + (i0 << 7));
        float a1 = *(const float*)(wrow + boff + (i1 << 7));
        float a2 = *(const float*)(wrow + boff + (i2 << 7));
        float a3 = *(const float*)(wrow + boff + (i3 << 7));
        a1 = w1_ ? a1 : 0.0f;
        a2 = w2_ ? a2 : 0.0f;
        a3 = w3_ ? a3 : 0.0f;
        acc0 += (double)a0;     // 4 independent chains
        acc1 += (double)a1;
        acc2 += (double)a2;
        acc3 += (double)a3;
      }
      w = (uint32_t)(mcur >> 32);
      boff = base0 + (32u << 7);
    }
    mcur = mnext;
  }
  double acc = (acc0 + acc1) + (acc2 + acc3);
  int hi2 = __shfl_xor(__double2hiint(acc), 32);
  int lo2 = __shfl_xor(__double2loint(acc), 32);
  acc += __hiloint2double(hi2, lo2);
  if (half == 0) part[wv][o] = acc;
  __syncthreads();
  if (wv < 4 && half == 0) {
    double tot = part[wv][o] + part[wv + 4][o];
    R[((size_t)b * HID + o) * NT + t] = tot;
  }
}

// ---------------- fast f64 psp+spike step: speculative-select short chain ----------------
#define SNN_FAST_STEP(rin, EMIT)                                                \
  {                                                                             \
    y2 = __builtin_fma(dsr, y2, w);          /* y2_t */                         \
    z2 = __builtin_fma(dsr, z2, (rin));      /* z2_t */                         \
    w  = dsr * z2;                                                              \
    double p  = ssr * y2;                                                       \
    double u0 = __builtin_fma(cr, q, p);                                        \
    double u1 = u0 + K;                                                         \
    double u  = sp ? u1 : u0;                                                   \
    bool s = (u >= 1.0);                                                        \
    double yr = q + (sp ? dre : 0.0);        /* yr_t */                         \
    double zr = zrd + (sp ? 1.0 : 0.0);      /* zr_{t-1} */                     \
    zrd = dre * zr;                                                             \
    q = __builtin_fma(dre, yr, dre * zrd);   /* q_t */                          \
    sp = s;                                                                     \
    EMIT                                                                        \
  }

// ---------------- K3: layer-2 psp+spike -> s2m[b][t] uint32 bitmask ----------------
__global__ __launch_bounds__(64) void k3_spike2(const double* __restrict__ R,
                                                uint32_t* __restrict__ s2m) {
  const int blk = blockIdx.x;
  const int lane = threadIdx.x;
  const int half = lane >> 5;
  const int b = blk * 2 + half;
  const int h = lane & 31;
  const double2* r2 = (const double2*)(R + ((size_t)b * HID + h) * NT);
  uint32_t* m0 = s2m + (size_t)(blk * 2) * NT;
  uint32_t* m1 = s2m + (size_t)(blk * 2 + 1) * NT;

  const double dsr = (double)D_SR, ssr = (double)S_SR;
  const double dre = (double)D_REF, cr = (double)C_REF;
  const double K = cr * dre;
  double y2 = 0, z2 = 0, w = 0, q = 0, zrd = 0;
  bool sp = false;

  double2 bufa[8], bufb[8];
#pragma unroll
  for (int i = 0; i < 8; i++) { bufa[i] = r2[i * 2]; bufb[i] = r2[i * 2 + 1]; }

  for (int g8 = 0; g8 < 16; g8++) {
#pragma unroll
    for (int j = 0; j < 8; j++) {
      const int g = g8 * 8 + j;
      if (g >= 125) break;
      const int t = g * 4;
      double2 va = bufa[j], vb = bufb[j];
      SNN_FAST_STEP(va.x, { uint64_t m = __ballot(s);
        if (lane == 0) { m0[t] = (uint32_t)m; m1[t] = (uint32_t)(m >> 32); } })
      SNN_FAST_STEP(va.y, { uint64_t m = __ballot(s);
        if (lane == 0) { m0[t + 1] = (uint32_t)m; m1[t + 1] = (uint32_t)(m >> 32); } })
      SNN_FAST_STEP(vb.x, { uint64_t m = __ballot(s);
        if (lane == 0) { m0[t + 2] = (uint32_t)m; m1[t + 2] = (uint32_t)(m >> 32); } })
      SNN_FAST_STEP(vb.y, { uint64_t m = __ballot(s);
        if (lane == 0) { m0[t + 3] = (uint32_t)m; m1[t + 3] = (uint32_t)(m >> 32); } })
      if (g + 8 < 125) { bufa[j] = r2[(g + 8) * 2]; bufb[j] = r2[(g + 8) * 2 + 1]; }
    }
  }
}

// ---------------- K4: R3[b,o,t] = sum_h w2[o,h]*s2[t,h] via mask (f64, asc h) ----------------
// 80k threads: divergent while-loop latency fully hidden by TLP.
__global__ __launch_bounds__(256) void k4_fc2(const float* __restrict__ w2,
                                              const uint32_t* __restrict__ s2m,
                                              double* __restrict__ R3) {
  __shared__ float w2l[NOUT * HID];
  const int tid = threadIdx.x;
  for (int i = tid; i < NOUT * HID; i += 256) w2l[i] = w2[i];
  __syncthreads();
  int id = blockIdx.x * 256 + tid;
  if (id >= NB * NOUT * NT) return;
  int t = id % NT;
  int bo = id / NT;
  int o = bo % NOUT;
  int b = bo / NOUT;
  uint32_t m = s2m[(size_t)b * NT + t];
  const float* wr = w2l + o * HID;
  double acc = 0.0;
  while (m) {
    uint32_t i0 = __builtin_ctz(m);                 uint32_t m1_ = m & (m - 1);
    uint32_t i1 = m1_ ? __builtin_ctz(m1_) : 0u;    uint32_t m2_ = m1_ ? (m1_ & (m1_ - 1)) : 0u;
    uint32_t i2 = m2_ ? __builtin_ctz(m2_) : 0u;    uint32_t m3_ = m2_ ? (m2_ & (m2_ - 1)) : 0u;
    uint32_t i3 = m3_ ? __builtin_ctz(m3_) : 0u;    m = m3_ ? (m3_ & (m3_ - 1)) : 0u;
    float a0 = wr[i0];
    float a1 = m1_ ? wr[i1] : 0.0f;
    float a2 = m2_ ? wr[i2] : 0.0f;
    float a3 = m3_ ? wr[i3] : 0.0f;
    acc += (double)a0;
    acc += (double)a1;
    acc += (double)a2;
    acc += (double)a3;
  }
  R3[id] = acc;   // [b][o][t] coalesced
}

// ---------------- K5: layer-3 psp+spike -> output f32 [b,o,t] ----------------
__global__ __launch_bounds__(64) void k5_out(const double* __restrict__ R3,
                                             float* __restrict__ out) {
  int id = blockIdx.x * 64 + threadIdx.x;
  if (id >= NB * NOUT) return;
  const double2* r2 = (const double2*)(R3 + (size_t)id * NT);
  float* orow = out + (size_t)id * NT;

  const double dsr = (double)D_SR, ssr = (double)S_SR;
  const double dre = (double)D_REF, cr = (double)C_REF;
  const double K = cr * dre;
  double y2 = 0, z2 = 0, w = 0, q = 0, zrd = 0;
  bool sp = false;

  double2 bufa[8], bufb[8];
#pragma unroll
  for (int i = 0; i < 8; i++) { bufa[i] = r2[i * 2]; bufb[i] = r2[i * 2 + 1]; }

  for (int g8 = 0; g8 < 16; g8++) {
#pragma unroll
    for (int j = 0; j < 8; j++) {
      const int g = g8 * 8 + j;
      if (g >= 125) break;
      double2 va = bufa[j], vb = bufb[j];
      float4 ov;
      SNN_FAST_STEP(va.x, { ov.x = s ? 1.0f : 0.0f; })
      SNN_FAST_STEP(va.y, { ov.y = s ? 1.0f : 0.0f; })
      SNN_FAST_STEP(vb.x, { ov.z = s ? 1.0f : 0.0f; })
      SNN_FAST_STEP(vb.y, { ov.w = s ? 1.0f : 0.0f; })
      *(float4*)(orow + g * 4) = ov;
      if (g + 8 < 125) { bufa[j] = r2[(g + 8) * 2]; bufb[j] = r2[(g + 8) * 2 + 1]; }
    }
  }
}

extern "C" void kernel_launch(void* const* d_in, const int* in_sizes, int n_in,
                              void* d_out, int out_size, void* d_ws, size_t ws_size,
                              hipStream_t stream) {
  const float* x  = (const float*)d_in[0];   // [8,6300,500]
  const float* w1 = (const float*)d_in[1];   // [32,6300]
  const float* w2 = (const float*)d_in[2];   // [20,32]
  float* out = (float*)d_out;                // [8,20,500]

  uint8_t* ws = (uint8_t*)d_ws;
  const size_t W1T_BYTES  = (size_t)F_IN * HID * 4;        //   806,400
  const size_t MASK_BYTES = (size_t)NB * NW * NT * 8;      // 3,168,000
  const size_t R_BYTES    = (size_t)NB * HID * NT * 8;     // 1,024,000
  const size_t S2M_BYTES  = (size_t)NB * NT * 4;           //    16,000
  float*    w1t   = (float*)ws;
  uint64_t* masks = (uint64_t*)(ws + W1T_BYTES);
  double*   R     = (double*)(ws + W1T_BYTES + MASK_BYTES);
  uint32_t* s2m   = (uint32_t*)(ws + W1T_BYTES + MASK_BYTES + R_BYTES);
  double*   R3    = (double*)(ws + W1T_BYTES + MASK_BYTES + R_BYTES + S2M_BYTES);

  k0_transpose<<<99, 256, 0, stream>>>(w1, w1t);
  k1_layer1<<<dim3(NW, NB), 64, 0, stream>>>(x, masks);
  k2_fc1<<<dim3(NB, NT / 4), 512, 0, stream>>>(w1t, masks, R);
  k3_spike2<<<4, 64, 0, stream>>>(R, s2m);
  k4_fc2<<<(NB * NOUT * NT + 255) / 256, 256, 0, stream>>>(w2, s2m, R3);
  k5_out<<<3, 64, 0, stream>>>(R3, out);
}